// Round 5
// baseline (410.931 us; speedup 1.0000x reference)
//
#include <hip/hip_runtime.h>
#include <stdint.h>

#define B_ROWS 16384
#define IN_DIM 1024
#define H_DIM  1024
#define KDIM   2048   // I + H
#define NDIM   4096   // 4*H
#define NT     64     // K / BK, BK = 32
#define LN_EPSF 1e-5f

typedef unsigned short u16;
typedef float  f32x4  __attribute__((ext_vector_type(4)));
typedef float  fv4    __attribute__((ext_vector_type(4)));
typedef __bf16 bf16x8 __attribute__((ext_vector_type(8)));
typedef u16    u16x4  __attribute__((ext_vector_type(4)));
typedef u16    u16x8  __attribute__((ext_vector_type(8)));

__device__ __forceinline__ u16 f2bf(float f) {
  unsigned u = __float_as_uint(f);
  u += 0x7FFFu + ((u >> 16) & 1u);   // RNE
  return (u16)(u >> 16);
}
__device__ __forceinline__ float bf2f(u16 s) {
  return __uint_as_float(((unsigned)s) << 16);
}

#define GLOAD_LDS16(gp, lp) __builtin_amdgcn_global_load_lds( \
    (__attribute__((address_space(1))) void*)(gp),            \
    (__attribute__((address_space(3))) void*)(lp), 16, 0, 0)

// ---------------- cast kernels ----------------
__global__ __launch_bounds__(256) void cast_concat(
    const float* __restrict__ x, const float* __restrict__ h,
    u16* __restrict__ cat) {
  int idx = blockIdx.x * 256 + threadIdx.x;
  long base = (long)idx * 8;
  int  c = (int)(base & (KDIM - 1));
  long b = base >> 11;
  const float* src = (c < IN_DIM) ? (x + b * IN_DIM + c)
                                  : (h + b * H_DIM + (c - IN_DIM));
  fv4 v0 = *(const fv4*)(src);
  fv4 v1 = *(const fv4*)(src + 4);
  u16x8 o;
  o[0]=f2bf(v0[0]); o[1]=f2bf(v0[1]); o[2]=f2bf(v0[2]); o[3]=f2bf(v0[3]);
  o[4]=f2bf(v1[0]); o[5]=f2bf(v1[1]); o[6]=f2bf(v1[2]); o[7]=f2bf(v1[3]);
  *(u16x8*)(cat + base) = o;
}

__global__ __launch_bounds__(256) void cast_plain(
    const float* __restrict__ w, u16* __restrict__ wb) {
  int idx = blockIdx.x * 256 + threadIdx.x;
  long base = (long)idx * 8;
  fv4 v0 = *(const fv4*)(w + base);
  fv4 v1 = *(const fv4*)(w + base + 4);
  u16x8 o;
  o[0]=f2bf(v0[0]); o[1]=f2bf(v0[1]); o[2]=f2bf(v0[2]); o[3]=f2bf(v0[3]);
  o[4]=f2bf(v1[0]); o[5]=f2bf(v1[1]); o[6]=f2bf(v1[2]); o[7]=f2bf(v1[3]);
  *(u16x8*)(wb + base) = o;
}

// ---------------- GEMM: C[M][N] = A[M][K] * B[N][K]^T ----------------
// 256x256 tile, BK=32, 8 waves (2Mx4N), 4-deep LDS ring, pipelined reg loads.
// m201-style barrier-pair phases: per K-tile 2 phases of
//   {gload || ds_read burst -> barrier -> setprio -> 16 MFMA -> setprio -> barrier}
// counted vmcnt(4) once per K-tile (guarantees tile t+2 resident, which body
// t+1's phase-1 register preload reads).
// T2 swizzle (16B-chunk units): c_phys = c ^ ((c>>3)&7), both sides.

#define BODY(J, CA, CB, NA, NB) do {                                         \
    const int t = tb + (J);                                                  \
    const bool st = (t + 3) < NT;                                            \
    const u16* __restrict__ ab  = &As[(J) & 3][0];                           \
    const u16* __restrict__ bb  = &Bs[(J) & 3][0];                           \
    const u16* __restrict__ abn = &As[((J) + 1) & 3][0];                     \
    const u16* __restrict__ bbn = &Bs[((J) + 1) & 3][0];                     \
    u16* __restrict__ sa = &As[((J) + 3) & 3][0];                            \
    u16* __restrict__ sb = &Bs[((J) + 3) & 3][0];                            \
    /* ---- phase 0: stage next-A ; read A47(this tile) ; MFMA cluster1 */   \
    if (st) {                                                                \
      GLOAD_LDS16(gA0 + (size_t)(t + 3) * 32, sa + tid * 8);                 \
      GLOAD_LDS16(gA1 + (size_t)(t + 3) * 32, sa + tid * 8 + 4096);          \
    }                                                                        \
    _Pragma("unroll")                                                        \
    for (int i = 0; i < 4; ++i)                                              \
      A47[i] = *(const bf16x8*)(ab + base_a + (4 + i) * 512);                \
    __builtin_amdgcn_sched_barrier(0);                                       \
    __builtin_amdgcn_s_barrier();                                            \
    __builtin_amdgcn_sched_barrier(0);                                       \
    __builtin_amdgcn_s_setprio(1);                                           \
    _Pragma("unroll")                                                        \
    for (int m = 0; m < 4; ++m)                                              \
      _Pragma("unroll")                                                      \
      for (int n = 0; n < 4; ++n)                                            \
        acc[m][n] = __builtin_amdgcn_mfma_f32_16x16x32_bf16(                 \
            CA[m], CB[n], acc[m][n], 0, 0, 0);                               \
    __builtin_amdgcn_s_setprio(0);                                           \
    __builtin_amdgcn_sched_barrier(0);                                       \
    __builtin_amdgcn_s_barrier();                                            \
    /* ---- phase 1: stage next-B ; read NA/NB(tile t+1) ; MFMA cluster2 */  \
    if (st) {                                                                \
      GLOAD_LDS16(gB0 + (size_t)(t + 3) * 32, sb + tid * 8);                 \
      GLOAD_LDS16(gB1 + (size_t)(t + 3) * 32, sb + tid * 8 + 4096);          \
    }                                                                        \
    if (t + 1 < NT) {                                                        \
      _Pragma("unroll")                                                      \
      for (int i = 0; i < 4; ++i) {                                          \
        NA[i] = *(const bf16x8*)(abn + base_a + i * 512);                    \
        NB[i] = *(const bf16x8*)(bbn + base_b + i * 512);                    \
      }                                                                      \
    }                                                                        \
    __builtin_amdgcn_sched_barrier(0);                                       \
    __builtin_amdgcn_s_barrier();                                            \
    __builtin_amdgcn_sched_barrier(0);                                       \
    __builtin_amdgcn_s_setprio(1);                                           \
    _Pragma("unroll")                                                        \
    for (int m = 0; m < 4; ++m)                                              \
      _Pragma("unroll")                                                      \
      for (int n = 0; n < 4; ++n)                                            \
        acc[4 + m][n] = __builtin_amdgcn_mfma_f32_16x16x32_bf16(             \
            A47[m], CB[n], acc[4 + m][n], 0, 0, 0);                          \
    __builtin_amdgcn_s_setprio(0);                                           \
    __builtin_amdgcn_sched_barrier(0);                                       \
    asm volatile("s_waitcnt vmcnt(4)" ::: "memory");                         \
    __builtin_amdgcn_s_barrier();                                            \
  } while (0)

__global__ __launch_bounds__(512, 2) void gemm_bt(
    const u16* __restrict__ A,   // [B_ROWS][KDIM]
    const u16* __restrict__ Bw,  // [NDIM][KDIM]
    u16* __restrict__ C) {       // [B_ROWS][NDIM] bf16
  __shared__ u16 As[4][8192];    // 4 stages x [256 rows][32 k] = 64 KB
  __shared__ u16 Bs[4][8192];    // 64 KB

  const int tid  = threadIdx.x;
  const int lane = tid & 63;
  const int wave = tid >> 6;
  const int wm   = wave >> 2;    // 0..1
  const int wn   = wave & 3;     // 0..3
  const int r    = lane & 15;
  const int g    = lane >> 4;    // 0..3

  // XCD-aware swizzle (1024 blocks, %8==0 -> bijective). m-fastest in chunk.
  const int bid = blockIdx.x;
  const int swz = (bid & 7) * 128 + (bid >> 3);
  const int row0 = (swz & 63) * 256;
  const int col0 = (swz >> 6) * 256;

  // staging with pre-swizzled global source: thread tid fills physical LDS
  // chunk tid; fetches logical chunk tid2 = tid ^ ((tid>>3)&7)
  const int tid2 = tid ^ ((tid >> 3) & 7);
  const u16* gA0 = A  + (size_t)(row0 + (tid2 >> 2)) * KDIM + (tid2 & 3) * 8;
  const u16* gA1 = gA0 + (size_t)128 * KDIM;
  const u16* gB0 = Bw + (size_t)(col0 + (tid2 >> 2)) * KDIM + (tid2 & 3) * 8;
  const u16* gB1 = gB0 + (size_t)128 * KDIM;

  // fragment LDS offsets (u16 units), read-side swizzle XOR (bits [5:3])
  const int rswz   = ((r >> 1) & 7) << 3;
  const int base_a = (((wm * 128 + r) * 32) + g * 8) ^ rswz;
  const int base_b = (((wn * 64  + r) * 32) + g * 8) ^ rswz;

  f32x4 acc[8][4] = {};
  bf16x8 XA[4], XB[4], YA[4], YB[4], A47[4];

  // ---- prologue: stage tiles 0,1,2; wait tiles 0,1; preload group0(0) ----
#pragma unroll
  for (int tt = 0; tt < 3; ++tt) {
    GLOAD_LDS16(gA0 + tt * 32, &As[tt][tid * 8]);
    GLOAD_LDS16(gA1 + tt * 32, &As[tt][tid * 8 + 4096]);
    GLOAD_LDS16(gB0 + tt * 32, &Bs[tt][tid * 8]);
    GLOAD_LDS16(gB1 + tt * 32, &Bs[tt][tid * 8 + 4096]);
  }
  asm volatile("s_waitcnt vmcnt(4)" ::: "memory");
  __builtin_amdgcn_s_barrier();
#pragma unroll
  for (int i = 0; i < 4; ++i) {
    XA[i] = *(const bf16x8*)(&As[0][0] + base_a + i * 512);
    XB[i] = *(const bf16x8*)(&Bs[0][0] + base_b + i * 512);
  }

  for (int u = 0; u < 16; ++u) {
    const int tb = u * 4;
    BODY(0, XA, XB, YA, YB);
    BODY(1, YA, YB, XA, XB);
    BODY(2, XA, XB, YA, YB);
    BODY(3, YA, YB, XA, XB);
  }

  // ---- epilogue: C/D layout col=lane&15, row=(lane>>4)*4+reg ----
#pragma unroll
  for (int m = 0; m < 8; ++m)
#pragma unroll
    for (int n = 0; n < 4; ++n)
#pragma unroll
      for (int q = 0; q < 4; ++q) {
        const int rr = row0 + wm * 128 + m * 16 + g * 4 + q;
        const int cc = col0 + wn * 64 + n * 16 + r;
        C[(size_t)rr * NDIM + cc] = f2bf(acc[m][n][q]);
      }
}

// ---------------- LN over 4096 + gates + LSTM update ----------------
__global__ __launch_bounds__(256) void ln_gates(
    const u16* __restrict__ t,       // [B_ROWS][NDIM] bf16
    const float* __restrict__ cell,  // [B_ROWS][H]
    const float* __restrict__ gamma, // [4][H]
    const float* __restrict__ beta,  // [4][H]
    float* __restrict__ out) {       // new_out | new_cell
  const int b   = blockIdx.x;
  const int tid = threadIdx.x;
  const int h0  = tid * 4;

  const u16* trow = t + (long)b * NDIM;
  float v[4][4];
#pragma unroll
  for (int gi = 0; gi < 4; ++gi) {
    u16x4 raw = *(const u16x4*)&trow[gi * H_DIM + h0];
#pragma unroll
    for (int j = 0; j < 4; ++j) v[gi][j] = bf2f(raw[j]);
  }

  float s1 = 0.f, s2 = 0.f;
#pragma unroll
  for (int gi = 0; gi < 4; ++gi)
#pragma unroll
    for (int j = 0; j < 4; ++j) { s1 += v[gi][j]; s2 += v[gi][j] * v[gi][j]; }

#pragma unroll
  for (int m = 32; m; m >>= 1) {
    s1 += __shfl_xor(s1, m);
    s2 += __shfl_xor(s2, m);
  }
  __shared__ float red[2][4];
  const int wave = tid >> 6, lane = tid & 63;
  if (lane == 0) { red[0][wave] = s1; red[1][wave] = s2; }
  __syncthreads();
  s1 = red[0][0] + red[0][1] + red[0][2] + red[0][3];
  s2 = red[1][0] + red[1][1] + red[1][2] + red[1][3];

  const float mean  = s1 * (1.f / (float)NDIM);
  const float var   = s2 * (1.f / (float)NDIM) - mean * mean;
  const float scale = rsqrtf(var + LN_EPSF);

  float hd[4][4];
#pragma unroll
  for (int gi = 0; gi < 4; ++gi) {
    fv4 gm = *(const fv4*)&gamma[gi * H_DIM + h0];
    fv4 bt = *(const fv4*)&beta[gi * H_DIM + h0];
#pragma unroll
    for (int j = 0; j < 4; ++j)
      hd[gi][j] = (v[gi][j] - mean) * scale * gm[j] + bt[j];
  }

  fv4 cv = *(const fv4*)&cell[(long)b * H_DIM + h0];
  fv4 no, nc;
#pragma unroll
  for (int j = 0; j < 4; ++j) {
    float fg = 1.f / (1.f + expf(-hd[0][j]));
    float ig = 1.f / (1.f + expf(-hd[1][j]));
    float og = 1.f / (1.f + expf(-hd[2][j]));
    float hc = 0.5f * hd[3][j] * (1.f + erff(hd[3][j] * 0.70710678118654752f));
    float ncell = fg * cv[j] + ig * hc;
    nc[j] = ncell;
    no[j] = og * ncell;
  }
  *(fv4*)&out[(long)b * H_DIM + h0] = no;
  *(fv4*)&out[(long)B_ROWS * H_DIM + (long)b * H_DIM + h0] = nc;
}

// ---------------- launch ----------------
extern "C" void kernel_launch(void* const* d_in, const int* in_sizes, int n_in,
                              void* d_out, int out_size, void* d_ws, size_t ws_size,
                              hipStream_t stream) {
  const float* x     = (const float*)d_in[0];
  const float* h     = (const float*)d_in[1];
  const float* cell  = (const float*)d_in[2];
  const float* W     = (const float*)d_in[3];
  const float* gamma = (const float*)d_in[4];
  const float* beta  = (const float*)d_in[5];
  float* out = (float*)d_out;

  const size_t cat_bytes = (size_t)B_ROWS * KDIM * sizeof(u16);  // 64 MB
  const size_t w_bytes   = (size_t)NDIM * KDIM * sizeof(u16);    // 16 MB
  const size_t t_bytes   = (size_t)B_ROWS * NDIM * sizeof(u16);  // 128 MB
  if (ws_size < cat_bytes + w_bytes + t_bytes) return;

  uint8_t* ws = (uint8_t*)d_ws;
  u16* catb = (u16*)ws;
  u16* Wb   = (u16*)(ws + cat_bytes);
  u16* tbuf = (u16*)(ws + cat_bytes + w_bytes);

  cast_concat<<<(B_ROWS * (long)KDIM / 8) / 256, 256, 0, stream>>>(x, h, catb);
  cast_plain<<<(NDIM * (long)KDIM / 8) / 256, 256, 0, stream>>>(W, Wb);

  gemm_bt<<<dim3(1024), 512, 0, stream>>>(catb, Wb, tbuf);

  ln_gates<<<B_ROWS, 256, 0, stream>>>(tbuf, cell, gamma, beta, out);
}

// Round 6
// 382.851 us; speedup vs baseline: 1.0733x; 1.0733x over previous
//
#include <hip/hip_runtime.h>
#include <stdint.h>

#define B_ROWS 16384
#define IN_DIM 1024
#define H_DIM  1024
#define KDIM   2048   // I + H
#define NDIM   4096   // 4*H
#define NT     64     // K / BK, BK = 32
#define LN_EPSF 1e-5f

typedef unsigned short u16;
typedef float  f32x4  __attribute__((ext_vector_type(4)));
typedef float  fv4    __attribute__((ext_vector_type(4)));
typedef __bf16 bf16x8 __attribute__((ext_vector_type(8)));
typedef u16    u16x4  __attribute__((ext_vector_type(4)));
typedef u16    u16x8  __attribute__((ext_vector_type(8)));

__device__ __forceinline__ u16 f2bf(float f) {
  unsigned u = __float_as_uint(f);
  u += 0x7FFFu + ((u >> 16) & 1u);   // RNE
  return (u16)(u >> 16);
}
__device__ __forceinline__ float bf2f(u16 s) {
  return __uint_as_float(((unsigned)s) << 16);
}

#define GLOAD_LDS16(gp, lp) __builtin_amdgcn_global_load_lds( \
    (__attribute__((address_space(1))) void*)(gp),            \
    (__attribute__((address_space(3))) void*)(lp), 16, 0, 0)

// ---------------- cast kernels ----------------
__global__ __launch_bounds__(256) void cast_concat(
    const float* __restrict__ x, const float* __restrict__ h,
    u16* __restrict__ cat) {
  int idx = blockIdx.x * 256 + threadIdx.x;
  long base = (long)idx * 8;
  int  c = (int)(base & (KDIM - 1));
  long b = base >> 11;
  const float* src = (c < IN_DIM) ? (x + b * IN_DIM + c)
                                  : (h + b * H_DIM + (c - IN_DIM));
  fv4 v0 = *(const fv4*)(src);
  fv4 v1 = *(const fv4*)(src + 4);
  u16x8 o;
  o[0]=f2bf(v0[0]); o[1]=f2bf(v0[1]); o[2]=f2bf(v0[2]); o[3]=f2bf(v0[3]);
  o[4]=f2bf(v1[0]); o[5]=f2bf(v1[1]); o[6]=f2bf(v1[2]); o[7]=f2bf(v1[3]);
  *(u16x8*)(cat + base) = o;
}

__global__ __launch_bounds__(256) void cast_plain(
    const float* __restrict__ w, u16* __restrict__ wb) {
  int idx = blockIdx.x * 256 + threadIdx.x;
  long base = (long)idx * 8;
  fv4 v0 = *(const fv4*)(w + base);
  fv4 v1 = *(const fv4*)(w + base + 4);
  u16x8 o;
  o[0]=f2bf(v0[0]); o[1]=f2bf(v0[1]); o[2]=f2bf(v0[2]); o[3]=f2bf(v0[3]);
  o[4]=f2bf(v1[0]); o[5]=f2bf(v1[1]); o[6]=f2bf(v1[2]); o[7]=f2bf(v1[3]);
  *(u16x8*)(wb + base) = o;
}

// ---------------- GEMM: C[M][N] = A[M][K] * B[N][K]^T ----------------
// 256x256 tile, BK=32, 8 waves (2Mx4N), 4-deep LDS ring, pipelined reg loads,
// one barrier + counted vmcnt(4) per K-tile (round-3 structure: best so far).
// T2 swizzle (16B-chunk units): c_phys = c ^ ((c>>3)&7), both sides.
// R6: col-fast XCD walk — each XCD's concurrent 32 blocks share a 2MB A-slice
// (L2-resident, A fetched once from HBM) and stream B (16MB) from L3.

#define BODY(J, CA, CB, NA, NB) do {                                         \
    const int t = tb + (J);                                                  \
    const bool st = (t + 3) < NT;                                            \
    const u16* __restrict__ ab  = &As[(J) & 3][0];                           \
    const u16* __restrict__ bb  = &Bs[(J) & 3][0];                           \
    const u16* __restrict__ abn = &As[((J) + 1) & 3][0];                     \
    const u16* __restrict__ bbn = &Bs[((J) + 1) & 3][0];                     \
    u16* __restrict__ sa = &As[((J) + 3) & 3][0];                            \
    u16* __restrict__ sb = &Bs[((J) + 3) & 3][0];                            \
    if (st) {                                                                \
      GLOAD_LDS16(gA0 + (size_t)(t + 3) * 32, sa + tid * 8);                 \
      GLOAD_LDS16(gA1 + (size_t)(t + 3) * 32, sa + tid * 8 + 4096);          \
    }                                                                        \
    _Pragma("unroll")                                                        \
    for (int i = 0; i < 4; ++i)                                              \
      A47[i] = *(const bf16x8*)(ab + base_a + (4 + i) * 512);                \
    __builtin_amdgcn_sched_barrier(0);                                       \
    __builtin_amdgcn_s_setprio(1);                                           \
    _Pragma("unroll")                                                        \
    for (int m = 0; m < 4; ++m)                                              \
      _Pragma("unroll")                                                      \
      for (int n = 0; n < 4; ++n)                                            \
        acc[m][n] = __builtin_amdgcn_mfma_f32_16x16x32_bf16(                 \
            CA[m], CB[n], acc[m][n], 0, 0, 0);                               \
    __builtin_amdgcn_s_setprio(0);                                           \
    __builtin_amdgcn_sched_barrier(0);                                       \
    if (st) {                                                                \
      GLOAD_LDS16(gB0 + (size_t)(t + 3) * 32, sb + tid * 8);                 \
      GLOAD_LDS16(gB1 + (size_t)(t + 3) * 32, sb + tid * 8 + 4096);          \
    }                                                                        \
    if (t + 1 < NT) {                                                        \
      _Pragma("unroll")                                                      \
      for (int i = 0; i < 4; ++i) {                                          \
        NA[i] = *(const bf16x8*)(abn + base_a + i * 512);                    \
        NB[i] = *(const bf16x8*)(bbn + base_b + i * 512);                    \
      }                                                                      \
    }                                                                        \
    __builtin_amdgcn_sched_barrier(0);                                       \
    __builtin_amdgcn_s_setprio(1);                                           \
    _Pragma("unroll")                                                        \
    for (int m = 0; m < 4; ++m)                                              \
      _Pragma("unroll")                                                      \
      for (int n = 0; n < 4; ++n)                                            \
        acc[4 + m][n] = __builtin_amdgcn_mfma_f32_16x16x32_bf16(             \
            A47[m], CB[n], acc[4 + m][n], 0, 0, 0);                          \
    __builtin_amdgcn_s_setprio(0);                                           \
    __builtin_amdgcn_sched_barrier(0);                                       \
    asm volatile("s_waitcnt vmcnt(4)" ::: "memory");                         \
    __builtin_amdgcn_s_barrier();                                            \
  } while (0)

__global__ __launch_bounds__(512, 2) void gemm_bt(
    const u16* __restrict__ A,   // [B_ROWS][KDIM]
    const u16* __restrict__ Bw,  // [NDIM][KDIM]
    u16* __restrict__ C) {       // [B_ROWS][NDIM] bf16
  __shared__ u16 As[4][8192];    // 4 stages x [256 rows][32 k] = 64 KB
  __shared__ u16 Bs[4][8192];    // 64 KB

  const int tid  = threadIdx.x;
  const int lane = tid & 63;
  const int wave = tid >> 6;
  const int wm   = wave >> 2;    // 0..1
  const int wn   = wave & 3;     // 0..3
  const int r    = lane & 15;
  const int g    = lane >> 4;    // 0..3

  // R6 col-fast XCD swizzle: XCD x (= bid&7) owns row panels x*8..x*8+7;
  // within XCD, col panel is the FAST index -> concurrent blocks share a
  // 2MB A-slice (L2-resident) and stream B from L3. Bijective: 8*8*16=1024.
  const int bid = blockIdx.x;
  const int xcd = bid & 7;
  const int k_  = bid >> 3;            // 0..127
  const int row0 = (xcd * 8 + (k_ >> 4)) * 256;
  const int col0 = (k_ & 15) * 256;

  // staging with pre-swizzled global source: thread tid fills physical LDS
  // chunk tid; fetches logical chunk tid2 = tid ^ ((tid>>3)&7)
  const int tid2 = tid ^ ((tid >> 3) & 7);
  const u16* gA0 = A  + (size_t)(row0 + (tid2 >> 2)) * KDIM + (tid2 & 3) * 8;
  const u16* gA1 = gA0 + (size_t)128 * KDIM;
  const u16* gB0 = Bw + (size_t)(col0 + (tid2 >> 2)) * KDIM + (tid2 & 3) * 8;
  const u16* gB1 = gB0 + (size_t)128 * KDIM;

  // fragment LDS offsets (u16 units), read-side swizzle XOR (bits [5:3])
  const int rswz   = ((r >> 1) & 7) << 3;
  const int base_a = (((wm * 128 + r) * 32) + g * 8) ^ rswz;
  const int base_b = (((wn * 64  + r) * 32) + g * 8) ^ rswz;

  f32x4 acc[8][4] = {};
  bf16x8 XA[4], XB[4], YA[4], YB[4], A47[4];

  // ---- prologue: stage tiles 0,1,2; wait tiles 0,1; preload group0(0) ----
#pragma unroll
  for (int tt = 0; tt < 3; ++tt) {
    GLOAD_LDS16(gA0 + tt * 32, &As[tt][tid * 8]);
    GLOAD_LDS16(gA1 + tt * 32, &As[tt][tid * 8 + 4096]);
    GLOAD_LDS16(gB0 + tt * 32, &Bs[tt][tid * 8]);
    GLOAD_LDS16(gB1 + tt * 32, &Bs[tt][tid * 8 + 4096]);
  }
  asm volatile("s_waitcnt vmcnt(4)" ::: "memory");
  __builtin_amdgcn_s_barrier();
#pragma unroll
  for (int i = 0; i < 4; ++i) {
    XA[i] = *(const bf16x8*)(&As[0][0] + base_a + i * 512);
    XB[i] = *(const bf16x8*)(&Bs[0][0] + base_b + i * 512);
  }

  for (int u = 0; u < 16; ++u) {
    const int tb = u * 4;
    BODY(0, XA, XB, YA, YB);
    BODY(1, YA, YB, XA, XB);
    BODY(2, XA, XB, YA, YB);
    BODY(3, YA, YB, XA, XB);
  }

  // ---- epilogue: C/D layout col=lane&15, row=(lane>>4)*4+reg ----
#pragma unroll
  for (int m = 0; m < 8; ++m)
#pragma unroll
    for (int n = 0; n < 4; ++n)
#pragma unroll
      for (int q = 0; q < 4; ++q) {
        const int rr = row0 + wm * 128 + m * 16 + g * 4 + q;
        const int cc = col0 + wn * 64 + n * 16 + r;
        C[(size_t)rr * NDIM + cc] = f2bf(acc[m][n][q]);
      }
}

// ---------------- LN over 4096 + gates + LSTM update ----------------
__global__ __launch_bounds__(256) void ln_gates(
    const u16* __restrict__ t,       // [B_ROWS][NDIM] bf16
    const float* __restrict__ cell,  // [B_ROWS][H]
    const float* __restrict__ gamma, // [4][H]
    const float* __restrict__ beta,  // [4][H]
    float* __restrict__ out) {       // new_out | new_cell
  const int b   = blockIdx.x;
  const int tid = threadIdx.x;
  const int h0  = tid * 4;

  const u16* trow = t + (long)b * NDIM;
  float v[4][4];
#pragma unroll
  for (int gi = 0; gi < 4; ++gi) {
    u16x4 raw = *(const u16x4*)&trow[gi * H_DIM + h0];
#pragma unroll
    for (int j = 0; j < 4; ++j) v[gi][j] = bf2f(raw[j]);
  }

  float s1 = 0.f, s2 = 0.f;
#pragma unroll
  for (int gi = 0; gi < 4; ++gi)
#pragma unroll
    for (int j = 0; j < 4; ++j) { s1 += v[gi][j]; s2 += v[gi][j] * v[gi][j]; }

#pragma unroll
  for (int m = 32; m; m >>= 1) {
    s1 += __shfl_xor(s1, m);
    s2 += __shfl_xor(s2, m);
  }
  __shared__ float red[2][4];
  const int wave = tid >> 6, lane = tid & 63;
  if (lane == 0) { red[0][wave] = s1; red[1][wave] = s2; }
  __syncthreads();
  s1 = red[0][0] + red[0][1] + red[0][2] + red[0][3];
  s2 = red[1][0] + red[1][1] + red[1][2] + red[1][3];

  const float mean  = s1 * (1.f / (float)NDIM);
  const float var   = s2 * (1.f / (float)NDIM) - mean * mean;
  const float scale = rsqrtf(var + LN_EPSF);

  float hd[4][4];
#pragma unroll
  for (int gi = 0; gi < 4; ++gi) {
    fv4 gm = *(const fv4*)&gamma[gi * H_DIM + h0];
    fv4 bt = *(const fv4*)&beta[gi * H_DIM + h0];
#pragma unroll
    for (int j = 0; j < 4; ++j)
      hd[gi][j] = (v[gi][j] - mean) * scale * gm[j] + bt[j];
  }

  fv4 cv = *(const fv4*)&cell[(long)b * H_DIM + h0];
  fv4 no, nc;
#pragma unroll
  for (int j = 0; j < 4; ++j) {
    float fg = 1.f / (1.f + expf(-hd[0][j]));
    float ig = 1.f / (1.f + expf(-hd[1][j]));
    float og = 1.f / (1.f + expf(-hd[2][j]));
    float hc = 0.5f * hd[3][j] * (1.f + erff(hd[3][j] * 0.70710678118654752f));
    float ncell = fg * cv[j] + ig * hc;
    nc[j] = ncell;
    no[j] = og * ncell;
  }
  *(fv4*)&out[(long)b * H_DIM + h0] = no;
  *(fv4*)&out[(long)B_ROWS * H_DIM + (long)b * H_DIM + h0] = nc;
}

// ---------------- launch ----------------
extern "C" void kernel_launch(void* const* d_in, const int* in_sizes, int n_in,
                              void* d_out, int out_size, void* d_ws, size_t ws_size,
                              hipStream_t stream) {
  const float* x     = (const float*)d_in[0];
  const float* h     = (const float*)d_in[1];
  const float* cell  = (const float*)d_in[2];
  const float* W     = (const float*)d_in[3];
  const float* gamma = (const float*)d_in[4];
  const float* beta  = (const float*)d_in[5];
  float* out = (float*)d_out;

  const size_t cat_bytes = (size_t)B_ROWS * KDIM * sizeof(u16);  // 64 MB
  const size_t w_bytes   = (size_t)NDIM * KDIM * sizeof(u16);    // 16 MB
  const size_t t_bytes   = (size_t)B_ROWS * NDIM * sizeof(u16);  // 128 MB
  if (ws_size < cat_bytes + w_bytes + t_bytes) return;

  uint8_t* ws = (uint8_t*)d_ws;
  u16* catb = (u16*)ws;
  u16* Wb   = (u16*)(ws + cat_bytes);
  u16* tbuf = (u16*)(ws + cat_bytes + w_bytes);

  cast_concat<<<(B_ROWS * (long)KDIM / 8) / 256, 256, 0, stream>>>(x, h, catb);
  cast_plain<<<(NDIM * (long)KDIM / 8) / 256, 256, 0, stream>>>(W, Wb);

  gemm_bt<<<dim3(1024), 512, 0, stream>>>(catb, Wb, tbuf);

  ln_gates<<<B_ROWS, 256, 0, stream>>>(tbuf, cell, gamma, beta, out);
}